// Round 6
// baseline (156.397 us; speedup 1.0000x reference)
//
#include <hip/hip_runtime.h>
#include <hip/hip_bf16.h>
#include <math.h>

typedef __attribute__((ext_vector_type(8))) __bf16 bf16x8;
typedef __attribute__((ext_vector_type(4))) float f32x4;

#define S_LEN 1024
#define D_MODEL 384
#define BATCH 32
#define N3 1152
#define KVB 32
#define NT (S_LEN / KVB)

#define MFMA16(a, b, c) __builtin_amdgcn_mfma_f32_16x16x32_bf16((a), (b), (c), 0, 0, 0)

static __device__ __forceinline__ ushort f2bf(float f) {
    __bf16 h = (__bf16)f;
    return __builtin_bit_cast(ushort, h);
}
static __device__ __forceinline__ uint pk2(float a, float b) {
    return (uint)f2bf(a) | ((uint)f2bf(b) << 16);
}

// ---------------- kernel 1: positional-encoding table, transposed peT[k][s] ----
__global__ void pe_kernel(float* peT) {
    int idx = blockIdx.x * 256 + threadIdx.x;      // 384*1024 total
    int k = idx >> 10, s = idx & 1023;
    float e = -(float)((k >> 1) * 2) * (logf(10000.0f) / (float)D_MODEL);
    float div = expf(e);
    float a = (float)s * div;
    peT[idx] = (k & 1) ? cosf(a) : sinf(a);
}

// ---------------- kernel 2: W [384][1152] f32 -> Wt [1152][384] bf16 ----------
__global__ void wt_kernel(const float* __restrict__ W, ushort* __restrict__ Wt) {
    __shared__ float tile[32][33];
    int n0 = blockIdx.x * 32, k0 = blockIdx.y * 32;
    int tx = threadIdx.x, ty = threadIdx.y;
#pragma unroll
    for (int r = 0; r < 4; ++r) {
        int kl = ty * 4 + r;
        tile[kl][tx] = W[(size_t)(k0 + kl) * N3 + n0 + tx];
    }
    __syncthreads();
#pragma unroll
    for (int r = 0; r < 4; ++r) {
        int nl = ty * 4 + r;
        Wt[(size_t)(n0 + nl) * D_MODEL + k0 + tx] = f2bf(tile[tx][nl]);
    }
}

// ---------------- kernel 3: A[m][k] = bf16(x[b][k][s] + peT[k][s]) ------------
__global__ void astage_kernel(const float* __restrict__ x, const float* __restrict__ peT,
                              ushort* __restrict__ A) {
    __shared__ float tile[32][33];
    int s0 = blockIdx.x * 32, k0 = blockIdx.y * 32, b = blockIdx.z;
    int tx = threadIdx.x, ty = threadIdx.y;
#pragma unroll
    for (int r = 0; r < 4; ++r) {
        int kl = ty * 4 + r;
        tile[kl][tx] = x[(size_t)(b * D_MODEL + k0 + kl) * S_LEN + s0 + tx]
                     + peT[(size_t)(k0 + kl) * S_LEN + s0 + tx];
    }
    __syncthreads();
#pragma unroll
    for (int r = 0; r < 4; ++r) {
        int sl = ty * 4 + r;
        A[(size_t)(b * S_LEN + s0 + sl) * D_MODEL + k0 + tx] = f2bf(tile[tx][sl]);
    }
}

// ---------------- kernel 4: qkv GEMM; V-range blocks write transposed Vt -----
__global__ __launch_bounds__(256) void qkv_gemm(const ushort* __restrict__ A,
                                                const ushort* __restrict__ Wt,
                                                const float* __restrict__ bias,
                                                ushort* __restrict__ qkv,
                                                ushort* __restrict__ Vt) {
    __shared__ __align__(16) ushort As[128 * 32];
    __shared__ __align__(16) ushort Bs[128 * 32];
    int id = blockIdx.x;                  // 2304 = 8 chunks * (9 n * 32 m)
    int g = id / 288, loc = id % 288;
    int nt_ = loc / 32, mt_ = g * 32 + (loc % 32);
    int m0 = mt_ * 128, n0 = nt_ * 128;
    int tid = threadIdx.x;
    int wave = tid >> 6, lane = tid & 63;
    int i16 = lane & 15, gq = lane >> 4;
    int wr = wave >> 1, wc = wave & 1;
    f32x4 acc[4][4] = {};
    for (int ks = 0; ks < 12; ++ks) {
        int k0 = ks * 32;
        __syncthreads();
#pragma unroll
        for (int i = 0; i < 2; ++i) {
            int off = (wave * 2 + i) * 1024;
            int row = (off >> 6) + (lane >> 2);
            int kc = lane & 3;
            const ushort* ga = A + (size_t)(m0 + row) * D_MODEL + k0 + kc * 8;
            __builtin_amdgcn_global_load_lds(
                (const __attribute__((address_space(1))) uint32_t*)ga,
                (__attribute__((address_space(3))) uint32_t*)((char*)As + off), 16, 0, 0);
            const ushort* gb = Wt + (size_t)(n0 + row) * D_MODEL + k0 + kc * 8;
            __builtin_amdgcn_global_load_lds(
                (const __attribute__((address_space(1))) uint32_t*)gb,
                (__attribute__((address_space(3))) uint32_t*)((char*)Bs + off), 16, 0, 0);
        }
        __syncthreads();
        bf16x8 af[4], bfr[4];
#pragma unroll
        for (int mt = 0; mt < 4; ++mt) {
            int row = wr * 64 + mt * 16 + i16;
            af[mt] = *reinterpret_cast<const bf16x8*>(&As[row * 32 + gq * 8]);
        }
#pragma unroll
        for (int nt = 0; nt < 4; ++nt) {
            int row = wc * 64 + nt * 16 + i16;
            bfr[nt] = *reinterpret_cast<const bf16x8*>(&Bs[row * 32 + gq * 8]);
        }
#pragma unroll
        for (int mt = 0; mt < 4; ++mt)
#pragma unroll
            for (int nt = 0; nt < 4; ++nt)
                acc[mt][nt] = MFMA16(af[mt], bfr[nt], acc[mt][nt]);
    }
    if (n0 < 2 * D_MODEL) {
#pragma unroll
        for (int nt = 0; nt < 4; ++nt) {
            int n = n0 + wc * 64 + nt * 16 + i16;
            float bv = bias[n];
#pragma unroll
            for (int mt = 0; mt < 4; ++mt)
#pragma unroll
                for (int r = 0; r < 4; ++r) {
                    int m = m0 + wr * 64 + mt * 16 + gq * 4 + r;
                    qkv[(size_t)m * N3 + n] = f2bf(acc[mt][nt][r] + bv);
                }
        }
    } else {
        // V range: write transposed Vt[b][c][s] directly (vtrans fused)
        int b = m0 >> 10;
        int s_base = (m0 & 1023) + wr * 64;
#pragma unroll
        for (int nt = 0; nt < 4; ++nt) {
            int n = n0 + wc * 64 + nt * 16 + i16;
            float bv = bias[n];
            int c = n - 2 * D_MODEL;
            ushort* vrow = Vt + (size_t)(b * D_MODEL + c) * S_LEN;
#pragma unroll
            for (int mt = 0; mt < 4; ++mt) {
                int s = s_base + mt * 16 + gq * 4;
                ushort4 p4;
                p4.x = f2bf(acc[mt][nt][0] + bv);
                p4.y = f2bf(acc[mt][nt][1] + bv);
                p4.z = f2bf(acc[mt][nt][2] + bv);
                p4.w = f2bf(acc[mt][nt][3] + bv);
                *reinterpret_cast<ushort4*>(vrow + s) = p4;
            }
        }
    }
}

// ---------------- kernel 5: flash attention v6 -------------------------------
// 512 blocks of 4 waves (64 q each) -> 2 independent blocks per CU: the two
// blocks' phases free-run against each other, covering stage-wait / softmax /
// barrier convoys (v3-v5 invariant: 1 lockstep block/CU, 57% issue-idle).
// Waves = 2 qg (32 q) x 2 h (j-half & c-half). Single-buffered K/V (53 KB LDS).
// K-stage(t+1) issued after B2 (K-reads done, overlaps PV); V-stage after B3.
// Fragment reuse: K/V-frag each feed 2 MFMAs (2 q-halves).
__global__ __launch_bounds__(256, 2) void attn_kernel(const ushort* __restrict__ qkv,
                                                      const ushort* __restrict__ Vt,
                                                      float* __restrict__ out) {
    __shared__ __align__(16) ushort Ks[12 * 32 * 32];      // 24 KB  [kt][32j][32k]
    __shared__ __align__(16) ushort Vts[384 * 32];         // 24 KB  [24ct][16c][32j]
    __shared__ __align__(16) ushort Pq[2][32 * 32];        // 4 KB: [qg][q 32][j 32]
    __shared__ float Ltab[2][2][2][16];                    // [qg][h][qh][i16]
    int id = blockIdx.x;                                   // 512 = 16 qt * 4 slot * 8 xcd
    int xcd = id & 7, slot = (id >> 3) & 3, qt = id >> 5;  // qt 0..15
    int b = slot * 8 + xcd;                                // batch grouped per XCD
    int tid = threadIdx.x;
    int wave = tid >> 6, lane = tid & 63;
    int i16 = lane & 15, gq = lane >> 4;
    int qg = wave & 1, h = wave >> 1;
    int q0w = qt * 64 + qg * 32;

    const ushort* Kbase = qkv + (size_t)b * S_LEN * N3 + D_MODEL;
    const ushort* Vbase = Vt + (size_t)b * D_MODEL * S_LEN;

    // K: 24 x 1KB subtiles, 6 per wave. V likewise.
    auto stage_K = [&](int kv0) {
#pragma unroll
        for (int r = 0; r < 6; ++r) {
            int ii = wave * 6 + r;                   // 0..23
            int kt = ii >> 1, jb = (ii & 1) * 16;
            int j = jb + (lane >> 2), ck = lane & 3;
            const ushort* ga = Kbase + (size_t)(kv0 + j) * N3 + kt * 32 + ck * 8;
            __builtin_amdgcn_global_load_lds(
                (const __attribute__((address_space(1))) uint32_t*)ga,
                (__attribute__((address_space(3))) uint32_t*)((char*)Ks + ii * 1024), 16, 0, 0);
        }
    };
    auto stage_V = [&](int kv0) {
#pragma unroll
        for (int r = 0; r < 6; ++r) {
            int ii = wave * 6 + r;
            int c = ii * 16 + (lane >> 2), ck = lane & 3;
            const ushort* ga = Vbase + (size_t)c * S_LEN + kv0 + ck * 8;
            __builtin_amdgcn_global_load_lds(
                (const __attribute__((address_space(1))) uint32_t*)ga,
                (__attribute__((address_space(3))) uint32_t*)((char*)Vts + ii * 1024), 16, 0, 0);
        }
    };

    stage_K(0);
    stage_V(0);

    // Q fragments (B-operand): lane (gq,i16): Q[q0w + qh*16 + i16][kt*32+gq*8..+8]
    bf16x8 qf[12][2];
    const ushort* Qb0 = qkv + (size_t)(b * S_LEN + q0w + i16) * N3;
    const ushort* Qb1 = qkv + (size_t)(b * S_LEN + q0w + 16 + i16) * N3;
#pragma unroll
    for (int kt = 0; kt < 12; ++kt) {
        qf[kt][0] = *reinterpret_cast<const bf16x8*>(Qb0 + kt * 32 + gq * 8);
        qf[kt][1] = *reinterpret_cast<const bf16x8*>(Qb1 + kt * 32 + gq * 8);
    }

    f32x4 oc[12][2] = {};
    float lsum0 = 0.f, lsum1 = 0.f;
    const float sl2e = 0.05103103630798287f * 1.4426950408889634f;

    char* PqB = (char*)&Pq[qg][0];       // this q-group's 2 KB P buffer

    for (int t = 0; t < NT; ++t) {
        asm volatile("s_waitcnt vmcnt(0)" ::: "memory");   // tile-t K/V landed
        __builtin_amdgcn_s_barrier();                      // B1
        __builtin_amdgcn_sched_barrier(0);

        // ---- QK: S[h*16..+16 j][32 q], K-frag feeds both q-halves ----
        const char* Kb = (const char*)Ks;
        f32x4 sacc0 = {}, sacc1 = {};
        __builtin_amdgcn_s_setprio(1);
#pragma unroll
        for (int kt = 0; kt < 12; ++kt) {
            bf16x8 kf = *reinterpret_cast<const bf16x8*>(
                Kb + kt * 2048 + (h * 16 + i16) * 64 + gq * 16);
            sacc0 = MFMA16(kf, qf[kt][0], sacc0);
            sacc1 = MFMA16(kf, qf[kt][1], sacc1);
        }
        __builtin_amdgcn_s_setprio(0);

        // ---- p = exp2(s*scale*log2e) (drop-max), accumulate l, write P ----
        float p00 = exp2f(sacc0[0] * sl2e), p01 = exp2f(sacc0[1] * sl2e);
        float p02 = exp2f(sacc0[2] * sl2e), p03 = exp2f(sacc0[3] * sl2e);
        float p10 = exp2f(sacc1[0] * sl2e), p11 = exp2f(sacc1[1] * sl2e);
        float p12 = exp2f(sacc1[2] * sl2e), p13 = exp2f(sacc1[3] * sl2e);
        lsum0 += (p00 + p01) + (p02 + p03);
        lsum1 += (p10 + p11) + (p12 + p13);
        {
            uint2 w0; w0.x = pk2(p00, p01); w0.y = pk2(p02, p03);
            uint2 w1; w1.x = pk2(p10, p11); w1.y = pk2(p12, p13);
            *reinterpret_cast<uint2*>(PqB + i16 * 64 + h * 32 + gq * 8) = w0;
            *reinterpret_cast<uint2*>(PqB + (16 + i16) * 64 + h * 32 + gq * 8) = w1;
        }
        asm volatile("s_waitcnt lgkmcnt(0)" ::: "memory"); // P visible
        __builtin_amdgcn_s_barrier();                      // B2: P ready, K-reads done
        __builtin_amdgcn_sched_barrier(0);
        if (t + 1 < NT) stage_K((t + 1) * KVB);            // overlaps PV; never drained here

        // ---- PV: O[h*192..+192 c][32 q] += V-half . P ----
        bf16x8 pf0 = *reinterpret_cast<const bf16x8*>(PqB + i16 * 64 + gq * 16);
        bf16x8 pf1 = *reinterpret_cast<const bf16x8*>(PqB + (16 + i16) * 64 + gq * 16);
        const char* Vb = (const char*)Vts;
        __builtin_amdgcn_s_setprio(1);
#pragma unroll
        for (int ct = 0; ct < 12; ++ct) {
            bf16x8 vf = *reinterpret_cast<const bf16x8*>(
                Vb + (h * 12 + ct) * 1024 + i16 * 64 + gq * 16);
            oc[ct][0] = MFMA16(vf, pf0, oc[ct][0]);
            oc[ct][1] = MFMA16(vf, pf1, oc[ct][1]);
        }
        __builtin_amdgcn_s_setprio(0);
        __builtin_amdgcn_s_barrier();                      // B3: V/P reads done
        __builtin_amdgcn_sched_barrier(0);
        if (t + 1 < NT) stage_V((t + 1) * KVB);            // exposed only across loop-top
    }

    // ---- l: reduce over gq (this wave's j-half), then cross-half via LDS ----
    lsum0 += __shfl_xor(lsum0, 16); lsum0 += __shfl_xor(lsum0, 32);
    lsum1 += __shfl_xor(lsum1, 16); lsum1 += __shfl_xor(lsum1, 32);
    __syncthreads();
    if (gq == 0) {
        Ltab[qg][h][0][i16] = lsum0;
        Ltab[qg][h][1][i16] = lsum1;
    }
    __syncthreads();
    float inv0 = 1.0f / (Ltab[qg][0][0][i16] + Ltab[qg][1][0][i16]);
    float inv1 = 1.0f / (Ltab[qg][0][1][i16] + Ltab[qg][1][1][i16]);

    // ---- store O: c = h*192 + ct*16 + gq*4 + r, q = q0w + qh*16 + i16 ----
    float* obase = out + (size_t)b * D_MODEL * S_LEN + q0w + i16;
#pragma unroll
    for (int ct = 0; ct < 12; ++ct)
#pragma unroll
        for (int r = 0; r < 4; ++r) {
            int c = h * 192 + ct * 16 + gq * 4 + r;
            obase[(size_t)c * S_LEN] = oc[ct][0][r] * inv0;
            obase[(size_t)c * S_LEN + 16] = oc[ct][1][r] * inv1;
        }
}

extern "C" void kernel_launch(void* const* d_in, const int* in_sizes, int n_in,
                              void* d_out, int out_size, void* d_ws, size_t ws_size,
                              hipStream_t stream) {
    const float* x    = (const float*)d_in[0];
    const float* W    = (const float*)d_in[1];
    const float* bias = (const float*)d_in[2];
    float* out = (float*)d_out;

    char* ws = (char*)d_ws;
    ushort* A_bf  = (ushort*)(ws);                                  // 25,165,824
    ushort* Wt    = (ushort*)(ws + 25165824);                       //    884,736
    float*  peT   = (float*)(ws + 26050560);                        //  1,572,864
    ushort* qkv   = (ushort*)(ws + 27623424);                       // 75,497,472
    ushort* Vt    = (ushort*)(ws + 103120896);                      // 25,165,824

    pe_kernel<<<1536, 256, 0, stream>>>(peT);
    wt_kernel<<<dim3(36, 12), dim3(32, 8), 0, stream>>>(W, Wt);
    astage_kernel<<<dim3(32, 12, 32), dim3(32, 8), 0, stream>>>(x, peT, A_bf);
    qkv_gemm<<<2304, 256, 0, stream>>>(A_bf, Wt, bias, qkv, Vt);
    attn_kernel<<<512, 256, 0, stream>>>(qkv, Vt, out);
}